// Round 7
// baseline (439.684 us; speedup 1.0000x reference)
//
#include <hip/hip_runtime.h>
#include <stdint.h>

#define GN 4008      // reference GRID
#define RPC 8        // rows per chunk
#define CH 501       // x chunks; CH*RPC == GN
#define CPAD 4096    // padded column dim
#define OWS 128      // occ words per row
#define PW 128       // PO words per row
#define TW 512       // y-tile width; 8 tiles
#define NBLK 1008    // grid blocks (<= 1024 co-residency capacity at 4/CU)
#define NTHR 256
#define NBAR 9
#define NGRP 28
#define GSZ 36       // NGRP*GSZ == NBLK
#define BKT 64       // per-chunk point bucket capacity
#define SSTR 16      // chunks per strip
#define NSTRIP 32
#define HPAD 4352    // CPAD + CPAD/16

static_assert(CH * RPC == GN, "chunking must cover grid");
static_assert(NGRP * GSZ == NBLK, "barrier groups must cover grid");

struct BarSt {
    int gcnt[NBAR][NGRP];
    int rcnt[NBAR];
    int flag[NBAR][NGRP * 16];   // 64B-strided wakeup flags
};

__global__ void k_init(int* __restrict__ p, int n) {
    int i = blockIdx.x * 256 + threadIdx.x;
    if (i < n) p[i] = 0;
}

__device__ __forceinline__ void gridbar(BarSt* B, int idx) {
    __syncthreads();
    if (threadIdx.x == 0) {
        __threadfence();                       // publish this block's writes
        int g = (int)blockIdx.x / GSZ;
        if (__hip_atomic_fetch_add(&B->gcnt[idx][g], 1, __ATOMIC_RELAXED,
                                   __HIP_MEMORY_SCOPE_AGENT) == GSZ - 1) {
            if (__hip_atomic_fetch_add(&B->rcnt[idx], 1, __ATOMIC_RELAXED,
                                       __HIP_MEMORY_SCOPE_AGENT) == NGRP - 1) {
                __threadfence();
                for (int k = 0; k < NGRP; ++k)
                    __hip_atomic_store(&B->flag[idx][k * 16], 1, __ATOMIC_RELAXED,
                                       __HIP_MEMORY_SCOPE_AGENT);
            }
        }
        while (__hip_atomic_load(&B->flag[idx][g * 16], __ATOMIC_RELAXED,
                                 __HIP_MEMORY_SCOPE_AGENT) == 0)
            __builtin_amdgcn_s_sleep(2);
        __threadfence();                       // acquire others' writes
    }
    __syncthreads();
}

__device__ __forceinline__ int clampI(int a) {
    return a < 0 ? 0 : (a > GN ? GN : a);
}

__global__ __launch_bounds__(NTHR, 4) void k_mega(
    const float* __restrict__ gt, int ngt,
    const float* __restrict__ pred, int npred,
    float* __restrict__ out,
    BarSt* __restrict__ bar, int* __restrict__ bktcnt, double* __restrict__ acc,
    uint32_t* __restrict__ cstage, uint16_t* __restrict__ bpts,
    int* __restrict__ Dcol, int* __restrict__ SSD,
    uint32_t* __restrict__ occw, uint32_t* __restrict__ colsum32,
    uint32_t* __restrict__ SSC, uint32_t* __restrict__ Vc32,
    int* __restrict__ Ic, uint64_t* __restrict__ PO)
{
    __shared__ int SH[4360];
    __shared__ int wsum4[4];
    __shared__ double redd[4];
    const int bid = blockIdx.x;
    const int t = threadIdx.x;

    // ---------------- P0: corners -> per-chunk buckets ---------------------
    // JAX scatter semantics: negative index wraps (+GN), still-OOB dropped.
    {
        int gi = bid * NTHR + t;
        if (gi < ngt) {
            float4 b = ((const float4*)gt)[gi];
            int x1 = (int)rintf(b.x * 100.0f);
            int y1 = (int)rintf(b.y * 100.0f);
            int x2 = (int)rintf(b.z * 100.0f);
            int y2 = (int)rintf(b.w * 100.0f);
            int xs[4] = {x1, x1, x2 + 1, x2 + 1};
            int ys[4] = {y1, y2 + 1, y1, y2 + 1};
            const uint32_t sb[4] = {1u, 0u, 0u, 1u};
            #pragma unroll
            for (int q = 0; q < 4; ++q) {
                int x = xs[q], y = ys[q];
                if (x < 0) x += GN;
                if (y < 0) y += GN;
                uint32_t pk = 0xFFFFFFFFu;
                if (x >= 0 && x < GN && y >= 0 && y < GN) {
                    pk = ((uint32_t)x << 13) | ((uint32_t)y << 1) | sb[q];
                    int c = x >> 3;
                    int pos = atomicAdd(&bktcnt[c], 1);
                    if (pos < BKT)
                        bpts[c * BKT + pos] =
                            (uint16_t)((((uint32_t)x & 7u) << 13) | ((uint32_t)y << 1) | sb[q]);
                    // pos >= BKT: dropped; readers detect via bktcnt[c] > BKT
                }
                cstage[gi * 4 + q] = pk;
            }
        }
    }
    gridbar(bar, 0);

    // ---------------- P1: per-chunk column histogram + h-scan -> Dcol ------
    if (bid < CH) {
        int c = bid;
        for (int i = t; i < HPAD; i += NTHR) SH[i] = 0;
        __syncthreads();
        int cnt = bktcnt[c];
        if (cnt <= BKT) {
            if (t < cnt) {
                uint32_t e = bpts[c * BKT + t];
                int y = (int)((e >> 1) & 0xFFFu);
                atomicAdd(&SH[y + (y >> 4)], (e & 1u) ? 1 : -1);
            }
        } else {    // overflow fallback: rescan all staged corners
            for (int i = t; i < 4 * ngt; i += NTHR) {
                uint32_t e = cstage[i];
                if (e != 0xFFFFFFFFu && ((int)(e >> 13) >> 3) == c) {
                    int y = (int)((e >> 1) & 0xFFFu);
                    atomicAdd(&SH[y + (y >> 4)], (e & 1u) ? 1 : -1);
                }
            }
        }
        __syncthreads();
        int v[16], s = 0;
        #pragma unroll
        for (int j = 0; j < 16; ++j) { s += SH[17 * t + j]; v[j] = s; }
        int lane = t & 63, wid = t >> 6;
        int ss = s;
        #pragma unroll
        for (int d = 1; d < 64; d <<= 1) {
            int tmp = __shfl_up(ss, d);
            if (lane >= d) ss += tmp;
        }
        if (lane == 63) wsum4[wid] = ss;
        __syncthreads();
        int carry = ss - s;
        #pragma unroll
        for (int w = 0; w < 4; ++w) if (w < wid) carry += wsum4[w];
        int4* o = (int4*)(Dcol + (size_t)c * CPAD + t * 16);
        #pragma unroll
        for (int q = 0; q < 4; ++q)
            o[q] = make_int4(v[4 * q + 0] + carry, v[4 * q + 1] + carry,
                             v[4 * q + 2] + carry, v[4 * q + 3] + carry);
    }
    gridbar(bar, 1);

    // ---------------- P2: strip sums of Dcol -> SSD ------------------------
    if (bid < NSTRIP * 16) {
        int s2 = bid >> 4;
        int col = (bid & 15) * 256 + t;
        int c0 = s2 * SSTR, c1 = min(CH, c0 + SSTR);
        int sum = 0;
        for (int c = c0; c < c1; ++c) sum += Dcol[(size_t)c * CPAD + col];
        SSD[(size_t)s2 * CPAD + col] = sum;
    }
    gridbar(bar, 2);

    // ---------------- P3: exclusive apply -> Dcol becomes Hpre -------------
    if (bid < NSTRIP * 16) {
        int s2 = bid >> 4;
        int col = (bid & 15) * 256 + t;
        int run = 0;
        for (int k = 0; k < s2; ++k) run += SSD[(size_t)k * CPAD + col];
        int c0 = s2 * SSTR, c1 = min(CH, c0 + SSTR);
        for (int c = c0; c < c1; ++c) {
            int tmp = Dcol[(size_t)c * CPAD + col];
            Dcol[(size_t)c * CPAD + col] = run;
            run += tmp;
        }
    }
    gridbar(bar, 3);

    // ---------------- P4: occ build, wave per (chunk, y-tile) --------------
    if (bid < 1002) {
        const int w = t >> 6, j = t & 63;
        const int tile = bid * 4 + w;           // 0..4007
        const int c = tile >> 3, tt = tile & 7;
        const int r0 = c * RPC, y0 = tt * TW;
        int* R = SH + w * 560;
        int* cD = R + 548;
        for (int i = j; i < 544; i += 64) R[i] = 0;
        if (j < 8) cD[j] = 0;
        int cnt = bktcnt[c];
        bool fb = (cnt > BKT);
        int pxr = -1, pry = 0, psg = 0;
        bool below = false, intile = false;
        if (!fb && j < cnt) {
            uint32_t e = bpts[c * BKT + j];
            int y = (int)((e >> 1) & 0xFFFu);
            pxr = (int)(e >> 13);
            psg = (e & 1u) ? 1 : -1;
            int ry = y - y0;
            if (ry >= 0 && ry < TW) { intile = true; pry = ry; }
            else if (ry < 0) below = true;
        }
        __syncthreads();
        if (below) atomicAdd(&cD[pxr], psg);
        if (fb) {
            for (int i = j; i < 4 * ngt; i += 64) {
                uint32_t e = cstage[i];
                if (e != 0xFFFFFFFFu) {
                    int x = (int)(e >> 13);
                    if ((x >> 3) == c) {
                        int y = (int)((e >> 1) & 0xFFFu);
                        if (y < y0) atomicAdd(&cD[x & 7], (e & 1u) ? 1 : -1);
                    }
                }
            }
        }
        const int4* hp = (const int4*)(Dcol + (size_t)c * CPAD + y0 + j * 8);
        int4 h0 = hp[0], h1 = hp[1];
        int h[8] = {h0.x, h0.y, h0.z, h0.w, h1.x, h1.y, h1.z, h1.w};
        __syncthreads();
        uint32_t cnt8[8] = {0, 0, 0, 0, 0, 0, 0, 0};
        int cb = 0;
        const int base = j * 8;
        for (int xr = 0; xr < RPC; ++xr) {
            if (intile && pxr == xr) atomicAdd(&R[pry + (pry >> 4)], psg);
            if (fb) {
                for (int i = j; i < 4 * ngt; i += 64) {
                    uint32_t e = cstage[i];
                    if (e != 0xFFFFFFFFu && (int)(e >> 13) == r0 + xr) {
                        int ry = (int)((e >> 1) & 0xFFFu) - y0;
                        if (ry >= 0 && ry < TW)
                            atomicAdd(&R[ry + (ry >> 4)], (e & 1u) ? 1 : -1);
                    }
                }
            }
            __syncthreads();
            cb += cD[xr];
            int v[8], sl = 0;
            #pragma unroll
            for (int k = 0; k < 8; ++k) {
                int a = base + k;
                sl += R[a + (a >> 4)];
                v[k] = sl;
            }
            int ss = sl;
            #pragma unroll
            for (int d = 1; d < 64; d <<= 1) {
                int tmp = __shfl_up(ss, d);
                if (j >= d) ss += tmp;
            }
            int excl = ss - sl + cb;
            uint32_t m = 0;
            #pragma unroll
            for (int k = 0; k < 8; ++k) {
                int gy = y0 + base + k;
                if (gy < GN && (h[k] + excl + v[k]) > 0) m |= (1u << k);
            }
            #pragma unroll
            for (int k = 0; k < 8; ++k) cnt8[k] += (m >> k) & 1u;
            uint32_t wq = m << (8 * (j & 3));
            wq |= __shfl_xor(wq, 1);
            wq |= __shfl_xor(wq, 2);
            if ((j & 3) == 0)
                occw[(size_t)(r0 + xr) * OWS + tt * 16 + (j >> 2)] = wq;
            __syncthreads();
        }
        uint4 cw;
        cw.x = cnt8[0] | (cnt8[1] << 16);
        cw.y = cnt8[2] | (cnt8[3] << 16);
        cw.z = cnt8[4] | (cnt8[5] << 16);
        cw.w = cnt8[6] | (cnt8[7] << 16);
        *(uint4*)(colsum32 + (((size_t)c * CPAD + y0 + base) >> 1)) = cw;
    }
    gridbar(bar, 4);

    // ---------------- P5: PO build (1002 tasks) || colsum strip sums (256) -
    for (int task = bid; task < 1258; task += NBLK) {
        if (task < 1002) {
            int w = t >> 6, j = t & 63;
            int x = task * 4 + w;
            uint2 wv = ((const uint2*)(occw + (size_t)x * OWS))[j];
            int p0 = __popc(wv.x), p1 = __popc(wv.y);
            int tot = p0 + p1;
            int ss = tot;
            #pragma unroll
            for (int d = 1; d < 64; d <<= 1) {
                int tmp = __shfl_up(ss, d);
                if (j >= d) ss += tmp;
            }
            int excl = ss - tot;
            ulonglong2 o;
            o.x = (uint64_t)wv.x | ((uint64_t)(uint32_t)excl << 48);
            o.y = (uint64_t)wv.y | ((uint64_t)(uint32_t)(excl + p0) << 48);
            ((ulonglong2*)(PO + (size_t)x * PW))[j] = o;
        } else {
            int b2 = task - 1002;
            int s2 = b2 >> 3;
            int wc = (b2 & 7) * 256 + t;
            int c0 = s2 * SSTR, c1 = min(CH, c0 + SSTR);
            uint32_t sum = 0;
            for (int c = c0; c < c1; ++c) sum += colsum32[(size_t)c * (CPAD / 2) + wc];
            SSC[(size_t)s2 * (CPAD / 2) + wc] = sum;
        }
    }
    gridbar(bar, 5);

    // ---------------- P6: exclusive strip apply -> Vc ----------------------
    if (bid < 256) {
        int s2 = bid >> 3;
        int wc = (bid & 7) * 256 + t;
        uint32_t run = 0;
        for (int k = 0; k < s2; ++k) run += SSC[(size_t)k * (CPAD / 2) + wc];
        int c0 = s2 * SSTR, c1 = min(CH, c0 + SSTR);
        for (int c = c0; c < c1; ++c) {
            Vc32[(size_t)c * (CPAD / 2) + wc] = run;
            run += colsum32[(size_t)c * (CPAD / 2) + wc];
        }
        if (c1 == CH) Vc32[(size_t)CH * (CPAD / 2) + wc] = run;
    }
    gridbar(bar, 6);

    // ---------------- P7: horizontal inclusive scan of Vc -> Ic ------------
    if (bid < CH + 1) {
        int c = bid;
        const int4* p = (const int4*)(Vc32 + (size_t)c * (CPAD / 2) + (size_t)t * 8);
        int4 A = p[0], B = p[1];
        uint32_t w[8] = {(uint32_t)A.x, (uint32_t)A.y, (uint32_t)A.z, (uint32_t)A.w,
                         (uint32_t)B.x, (uint32_t)B.y, (uint32_t)B.z, (uint32_t)B.w};
        int v[16], s = 0;
        #pragma unroll
        for (int q = 0; q < 8; ++q) {
            s += (int)(w[q] & 0xFFFFu); v[2 * q] = s;
            s += (int)(w[q] >> 16);     v[2 * q + 1] = s;
        }
        int lane = t & 63, wid = t >> 6;
        int ss = s;
        #pragma unroll
        for (int d = 1; d < 64; d <<= 1) {
            int tmp = __shfl_up(ss, d);
            if (lane >= d) ss += tmp;
        }
        if (lane == 63) wsum4[wid] = ss;
        __syncthreads();
        int carry = ss - s;
        #pragma unroll
        for (int w2 = 0; w2 < 4; ++w2) if (w2 < wid) carry += wsum4[w2];
        int4* o = (int4*)(Ic + (size_t)c * CPAD + (size_t)t * 16);
        #pragma unroll
        for (int q = 0; q < 4; ++q)
            o[q] = make_int4(v[4 * q + 0] + carry, v[4 * q + 1] + carry,
                             v[4 * q + 2] + carry, v[4 * q + 3] + carry);
    }
    gridbar(bar, 7);

    // ---------------- P8: gather (thread per box-corner) + reduce ----------
    if (bid < (4 * npred + NTHR - 1) / NTHR) {
        int g = bid * NTHR + t;
        int i = g >> 2, k = g & 3;
        double l = 0.0;
        int x1 = 0, y1 = 0, x2 = 0, y2 = 0;
        int cov = 0;
        if (i < npred) {
            float4 bx = ((const float4*)pred)[i];
            x1 = (int)rintf(bx.x * 100.0f);
            y1 = (int)rintf(bx.y * 100.0f);
            x2 = (int)rintf(bx.z * 100.0f);
            y2 = (int)rintf(bx.w * 100.0f);
            int a1 = clampI(x1), b1 = clampI(y1), a2 = clampI(x2), b2 = clampI(y2);
            int a = (k & 1) ? a1 : a2;
            int b = (k & 2) ? b1 : b2;
            int sgn = ((k ^ (k >> 1)) & 1) ? -1 : 1;
            int Iv = 0;
            if (a > 0 && b > 0) {
                int c = a >> 3;
                Iv = Ic[(size_t)c * CPAD + (b - 1)];
                int bw = b >> 5;
                uint32_t mask = (1u << (b & 31)) - 1u;   // b&31==0 -> 0
                for (int x = (a & ~7); x < a; ++x) {
                    uint64_t po = PO[(size_t)x * PW + bw];
                    Iv += (int)(po >> 48) + __popc((uint32_t)po & mask);
                }
            }
            cov = sgn * Iv;
        }
        cov += __shfl_xor(cov, 1);
        cov += __shfl_xor(cov, 2);
        if (i < npred && k == 0) {
            int area = (x2 - x1) * (y2 - y1);
            bool valid = (x2 > x1) && (y2 > y1);
            float iou = valid ? ((float)cov / fmaxf((float)area, 1.0f)) : 0.0f;
            l = (double)(1.0f - iou);
        }
        #pragma unroll
        for (int d = 32; d > 0; d >>= 1) l += __shfl_down(l, d);
        int lane = t & 63, wid = t >> 6;
        if (lane == 0) redd[wid] = l;
        __syncthreads();
        if (t == 0)
            atomicAdd(acc, redd[0] + redd[1] + redd[2] + redd[3]);
    }
    gridbar(bar, 8);

    // ---------------- P9: finalize -----------------------------------------
    if (bid == 0 && t == 0)
        out[0] = (float)(*acc / (double)npred);
}

extern "C" void kernel_launch(void* const* d_in, const int* in_sizes, int n_in,
                              void* d_out, int out_size, void* d_ws, size_t ws_size,
                              hipStream_t stream) {
    const float* pred = (const float*)d_in[0];
    // d_in[1] = target, unused by the reference loss
    const float* gt = (const float*)d_in[2];
    int npred = in_sizes[0] / 4;
    int ngt = in_sizes[2] / 4;

    char* ws = (char*)d_ws;
    size_t off = 0;
    auto alloc = [&](size_t bytes) {
        void* p = ws + off;
        off = (off + bytes + 255) & ~(size_t)255;
        return p;
    };
    BarSt* bar = (BarSt*)alloc(sizeof(BarSt));
    int* bktcnt = (int*)alloc(512 * sizeof(int));
    double* acc = (double*)alloc(sizeof(double));
    size_t hdrInts = off / 4;                       // zeroed by k_init each call
    uint32_t* cstage = (uint32_t*)alloc((size_t)4 * ngt * sizeof(uint32_t));
    uint16_t* bpts = (uint16_t*)alloc((size_t)CH * BKT * sizeof(uint16_t));
    int* Dcol = (int*)alloc((size_t)CH * CPAD * sizeof(int));          // becomes Hpre
    int* SSD = (int*)alloc((size_t)NSTRIP * CPAD * sizeof(int));
    uint32_t* occw = (uint32_t*)alloc((size_t)GN * OWS * sizeof(uint32_t));
    uint32_t* colsum = (uint32_t*)alloc((size_t)CH * (CPAD / 2) * sizeof(uint32_t));
    uint32_t* SSC = (uint32_t*)alloc((size_t)NSTRIP * (CPAD / 2) * sizeof(uint32_t));
    uint32_t* Vc = (uint32_t*)alloc((size_t)(CH + 1) * (CPAD / 2) * sizeof(uint32_t));
    int* Ic = (int*)alloc((size_t)(CH + 1) * CPAD * sizeof(int));
    uint64_t* PO = (uint64_t*)alloc((size_t)GN * PW * sizeof(uint64_t));

    k_init<<<dim3((unsigned)((hdrInts + 255) / 256)), dim3(256), 0, stream>>>(
        (int*)ws, (int)hdrInts);
    k_mega<<<dim3(NBLK), dim3(NTHR), 0, stream>>>(
        gt, ngt, pred, npred, (float*)d_out,
        bar, bktcnt, acc, cstage, bpts, Dcol, SSD,
        occw, colsum, SSC, Vc, Ic, PO);
}

// Round 8
// 59.298 us; speedup vs baseline: 7.4148x; 7.4148x over previous
//
#include <hip/hip_runtime.h>
#include <stdint.h>

#define GN 4008      // reference GRID
#define RPC 8        // rows per chunk
#define CH 501       // x chunks; CH*RPC == GN
#define CPAD 4096    // padded column dim
#define PW 128       // PO u64 words per row
#define TW 512       // y-tile width; 8 tiles per row
#define HPAD 4352    // CPAD + CPAD/16
#define BKT 96       // per-chunk bucket capacity (mean ~16, wrap-heavy ~30)

static_assert(CH * RPC == GN, "chunking must cover grid");

// Corner q of a box, JAX scatter semantics: negative index wraps (+GN),
// still-OOB (>=GN) dropped. q: 0=(x1,y1,+) 1=(x1,y2+1,-) 2=(x2+1,y1,-) 3=(x2+1,y2+1,+)
__device__ __forceinline__ bool corner1(const float4 b, int q,
                                        int& x, int& y, int& sg) {
    int x1 = (int)rintf(b.x * 100.0f);
    int y1 = (int)rintf(b.y * 100.0f);
    int x2 = (int)rintf(b.z * 100.0f);
    int y2 = (int)rintf(b.w * 100.0f);
    x = (q & 2) ? (x2 + 1) : x1;
    y = (q & 1) ? (y2 + 1) : y1;
    sg = (q == 0 || q == 3) ? 1 : -1;
    if (x < 0) x += GN;
    if (y < 0) y += GN;
    return (x >= 0 && x < GN && y >= 0 && y < GN);
}

// ---------------- K1: per-chunk corner histogram + h-scan + bucket ---------
// Block c derives all corners from gt (L2-resident), keeps chunk c's.
__global__ __launch_bounds__(256) void k_build(const float* __restrict__ gt, int ngt,
                                               int* __restrict__ Dcol,
                                               int* __restrict__ bktcnt,
                                               uint16_t* __restrict__ bpts,
                                               double* __restrict__ acc,
                                               int* __restrict__ done) {
    __shared__ int H[HPAD];
    __shared__ int wsum4[4];
    __shared__ int lcnt;
    int c = blockIdx.x, t = threadIdx.x;
    for (int i = t; i < HPAD; i += 256) H[i] = 0;
    if (t == 0) lcnt = 0;
    if (c == 0 && t == 0) { *acc = 0.0; *done = 0; }
    __syncthreads();
    for (int i = t; i < ngt; i += 256) {
        float4 b = ((const float4*)gt)[i];
        #pragma unroll
        for (int q = 0; q < 4; ++q) {
            int x, y, sg;
            if (corner1(b, q, x, y, sg) && (x >> 3) == c) {
                atomicAdd(&H[y + (y >> 4)], sg);
                int pos = atomicAdd(&lcnt, 1);
                if (pos < BKT)
                    bpts[c * BKT + pos] =
                        (uint16_t)(((x & 7) << 13) | (y << 1) | (sg > 0 ? 1 : 0));
            }
        }
    }
    __syncthreads();
    if (t == 0) bktcnt[c] = lcnt;
    int v[16], s = 0;
    #pragma unroll
    for (int j = 0; j < 16; ++j) { s += H[17 * t + j]; v[j] = s; }
    int lane = t & 63, wid = t >> 6;
    int ss = s;
    #pragma unroll
    for (int d = 1; d < 64; d <<= 1) {
        int tmp = __shfl_up(ss, d);
        if (lane >= d) ss += tmp;
    }
    if (lane == 63) wsum4[wid] = ss;
    __syncthreads();
    int carry = ss - s;
    #pragma unroll
    for (int w = 0; w < 4; ++w) if (w < wid) carry += wsum4[w];
    int4* o = (int4*)(Dcol + (size_t)c * CPAD + t * 16);
    #pragma unroll
    for (int q = 0; q < 4; ++q)
        o[q] = make_int4(v[4 * q + 0] + carry, v[4 * q + 1] + carry,
                         v[4 * q + 2] + carry, v[4 * q + 3] + carry);
}

// ---------------- K2: vertical exclusive scan (single dispatch) ------------
// Dcol -> Hpre in place. 128 blocks x 512 thr; block owns 32 cols, 16 segs.
__global__ __launch_bounds__(512) void k_vscanD(int* __restrict__ D) {
    __shared__ int ssum[16][32];
    int w = threadIdx.x & 31, s = threadIdx.x >> 5;
    int col = blockIdx.x * 32 + w;
    int c0 = s * 32, c1 = min(CH, c0 + 32);
    int sum = 0;
    for (int c = c0; c < c1; ++c) sum += D[(size_t)c * CPAD + col];
    ssum[s][w] = sum;
    __syncthreads();
    int run = 0;
    for (int k = 0; k < s; ++k) run += ssum[k][w];
    for (int c = c0; c < c1; ++c) {
        int tmp = D[(size_t)c * CPAD + col];
        D[(size_t)c * CPAD + col] = run;
        run += tmp;
    }
}

// ---------------- K3: occ + PO + Crow, block per chunk ---------------------
// 512 thr = 8 waves; wave tt owns y-tile [tt*512,(tt+1)*512). Occ words stay
// in LDS; PO (word-popc prefix, u64) and Crow (h-scanned column counts, u16
// packed) are emitted directly.
__global__ __launch_bounds__(512) void k_occ(const float* __restrict__ gt, int ngt,
                                             const uint16_t* __restrict__ bpts,
                                             const int* __restrict__ bktcnt,
                                             const int* __restrict__ Hpre,
                                             uint64_t* __restrict__ PO,
                                             uint32_t* __restrict__ Crow32) {
    __shared__ int SH[8 * 560];
    __shared__ uint32_t owq[8 * 128];
    __shared__ int wtot[8];
    int c = blockIdx.x, t = threadIdx.x;
    int tt = t >> 6, j = t & 63;
    int r0 = c * RPC, y0 = tt * TW;
    int* R = SH + tt * 560;       // wave-private running column sums (padded)
    int* cD = R + 544;            // wave-private per-row carry (cols < y0)
    for (int i = j; i < 544; i += 64) R[i] = 0;
    if (j < 8) cD[j] = 0;
    int cnt = bktcnt[c];
    bool fb = cnt > BKT;
    int pxr0 = -1, pry0 = 0, psg0 = 0;
    int pxr1 = -1, pry1 = 0, psg1 = 0;
    if (!fb) {
        if (j < cnt) {
            uint32_t e = bpts[c * BKT + j];
            int y = (int)((e >> 1) & 0xFFFu), xr = (int)(e >> 13);
            int sg = (e & 1u) ? 1 : -1;
            int ry = y - y0;
            if (ry >= 0 && ry < TW) { pxr0 = xr; pry0 = ry; psg0 = sg; }
            else if (ry < 0) atomicAdd(&cD[xr], sg);
        }
        if (j + 64 < cnt) {
            uint32_t e = bpts[c * BKT + j + 64];
            int y = (int)((e >> 1) & 0xFFFu), xr = (int)(e >> 13);
            int sg = (e & 1u) ? 1 : -1;
            int ry = y - y0;
            if (ry >= 0 && ry < TW) { pxr1 = xr; pry1 = ry; psg1 = sg; }
            else if (ry < 0) atomicAdd(&cD[xr], sg);
        }
    } else {    // overflow fallback (correctness only): re-derive from gt
        for (int i = j; i < 4 * ngt; i += 64) {
            float4 b = ((const float4*)gt)[i >> 2];
            int x, y, sg;
            if (corner1(b, i & 3, x, y, sg) && (x >> 3) == c) {
                int ry = y - y0;
                if (ry < 0) atomicAdd(&cD[x & 7], sg);
            }
        }
    }
    const int4* hp = (const int4*)(Hpre + (size_t)c * CPAD + y0 + j * 8);
    int4 h0 = hp[0], h1 = hp[1];
    int h[8] = {h0.x, h0.y, h0.z, h0.w, h1.x, h1.y, h1.z, h1.w};
    __syncthreads();
    uint32_t cnt8[8] = {0, 0, 0, 0, 0, 0, 0, 0};
    int cb = 0;
    const int base = j * 8;
    for (int xr = 0; xr < RPC; ++xr) {
        if (pxr0 == xr) atomicAdd(&R[pry0 + (pry0 >> 4)], psg0);
        if (pxr1 == xr) atomicAdd(&R[pry1 + (pry1 >> 4)], psg1);
        if (fb) {
            for (int i = j; i < 4 * ngt; i += 64) {
                float4 b = ((const float4*)gt)[i >> 2];
                int x, y, sg;
                if (corner1(b, i & 3, x, y, sg) && x == r0 + xr) {
                    int ry = y - y0;
                    if (ry >= 0 && ry < TW) atomicAdd(&R[ry + (ry >> 4)], sg);
                }
            }
        }
        __syncthreads();
        cb += cD[xr];
        int v[8], sl = 0;
        #pragma unroll
        for (int k = 0; k < 8; ++k) {
            int a = base + k;
            sl += R[a + (a >> 4)];
            v[k] = sl;
        }
        int ss = sl;
        #pragma unroll
        for (int d = 1; d < 64; d <<= 1) {
            int tmp = __shfl_up(ss, d);
            if (j >= d) ss += tmp;
        }
        int excl = ss - sl + cb;
        uint32_t m = 0;
        #pragma unroll
        for (int k = 0; k < 8; ++k) {
            int gy = y0 + base + k;
            if (gy < GN && (h[k] + excl + v[k]) > 0) m |= (1u << k);
        }
        #pragma unroll
        for (int k = 0; k < 8; ++k) cnt8[k] += (m >> k) & 1u;
        uint32_t wq = m << (8 * (j & 3));
        wq |= __shfl_xor(wq, 1);
        wq |= __shfl_xor(wq, 2);
        if ((j & 3) == 0)
            owq[xr * 128 + tt * 16 + (j >> 2)] = wq;
        __syncthreads();
    }
    // PO: wave tt emits row r0+tt (reads owq across all tiles -> barrier'd)
    {
        uint32_t w0 = owq[tt * 128 + 2 * j];
        uint32_t w1 = owq[tt * 128 + 2 * j + 1];
        int p0 = __popc(w0), p1 = __popc(w1);
        int tot = p0 + p1;
        int ss = tot;
        #pragma unroll
        for (int d = 1; d < 64; d <<= 1) {
            int tmp = __shfl_up(ss, d);
            if (j >= d) ss += tmp;
        }
        int excl = ss - tot;
        ulonglong2 o;
        o.x = (uint64_t)w0 | ((uint64_t)(uint32_t)excl << 48);
        o.y = (uint64_t)w1 | ((uint64_t)(uint32_t)(excl + p0) << 48);
        ((ulonglong2*)(PO + (size_t)(r0 + tt) * PW))[j] = o;
    }
    // Crow: block-wide h-scan of per-column chunk counts (u16 packed)
    {
        int ctot = 0;
        #pragma unroll
        for (int k = 0; k < 8; ++k) ctot += (int)cnt8[k];
        int ss = ctot;
        #pragma unroll
        for (int d = 1; d < 64; d <<= 1) {
            int tmp = __shfl_up(ss, d);
            if (j >= d) ss += tmp;
        }
        if (j == 63) wtot[tt] = ss;
        __syncthreads();
        int run = ss - ctot;
        #pragma unroll
        for (int w = 0; w < 8; ++w) if (w < tt) run += wtot[w];
        uint32_t pk[4];
        #pragma unroll
        for (int p = 0; p < 4; ++p) {
            run += (int)cnt8[2 * p];
            uint32_t lo = (uint32_t)run & 0xFFFFu;
            run += (int)cnt8[2 * p + 1];
            pk[p] = lo | (((uint32_t)run & 0xFFFFu) << 16);
        }
        *(uint4*)(Crow32 + (((size_t)c * CPAD + y0 + base) >> 1)) =
            make_uint4(pk[0], pk[1], pk[2], pk[3]);
    }
}

// ---------------- K4: vertical exclusive scan of Crow -> Ic ----------------
// 128 blocks x 512 thr; block owns 16 packed words (32 cols), 32 segs of 16.
__global__ __launch_bounds__(512) void k_vscanC(const uint32_t* __restrict__ Crow32,
                                                int* __restrict__ Ic) {
    __shared__ uint32_t ssum[32][16][2];
    int w = threadIdx.x & 15, s = threadIdx.x >> 4;
    int word = blockIdx.x * 16 + w;
    int c0 = s * 16, c1 = min(CH, c0 + 16);
    uint32_t s0 = 0, s1 = 0;
    for (int c = c0; c < c1; ++c) {
        uint32_t v = Crow32[(size_t)c * (CPAD / 2) + word];
        s0 += v & 0xFFFFu;
        s1 += v >> 16;
    }
    ssum[s][w][0] = s0;
    ssum[s][w][1] = s1;
    __syncthreads();
    uint32_t r0 = 0, r1 = 0;
    for (int k = 0; k < s; ++k) { r0 += ssum[k][w][0]; r1 += ssum[k][w][1]; }
    for (int c = c0; c < c1; ++c) {
        *(int2*)(Ic + (size_t)c * CPAD + 2 * word) = make_int2((int)r0, (int)r1);
        uint32_t v = Crow32[(size_t)c * (CPAD / 2) + word];
        r0 += v & 0xFFFFu;
        r1 += v >> 16;
    }
    if (c1 == CH)
        *(int2*)(Ic + (size_t)CH * CPAD + 2 * word) = make_int2((int)r0, (int)r1);
}

// ---------------- K5: gather (thread per box-corner) + reduce + finalize ---
__device__ __forceinline__ int clampI(int a) {
    return a < 0 ? 0 : (a > GN ? GN : a);
}

__global__ __launch_bounds__(256) void k_gather(const float* __restrict__ pred, int npred,
                                                const int* __restrict__ Ic,
                                                const uint64_t* __restrict__ PO,
                                                double* __restrict__ acc,
                                                int* __restrict__ done,
                                                float* __restrict__ out, int nblocks) {
    __shared__ double red[4];
    int g = blockIdx.x * 256 + threadIdx.x;
    int i = g >> 2, k = g & 3;
    double l = 0.0;
    int x1 = 0, y1 = 0, x2 = 0, y2 = 0;
    int cov = 0;
    if (i < npred) {
        float4 bx = ((const float4*)pred)[i];
        x1 = (int)rintf(bx.x * 100.0f);
        y1 = (int)rintf(bx.y * 100.0f);
        x2 = (int)rintf(bx.z * 100.0f);
        y2 = (int)rintf(bx.w * 100.0f);
        int a1 = clampI(x1), b1 = clampI(y1), a2 = clampI(x2), b2 = clampI(y2);
        int a = (k & 1) ? a1 : a2;
        int b = (k & 2) ? b1 : b2;
        int sgn = ((k ^ (k >> 1)) & 1) ? -1 : 1;
        int Iv = 0;
        if (a > 0 && b > 0) {
            int c = a >> 3;
            Iv = Ic[(size_t)c * CPAD + (b - 1)];
            int bw = b >> 5;
            uint32_t mask = (1u << (b & 31)) - 1u;   // b&31==0 -> 0
            for (int x = (a & ~7); x < a; ++x) {
                uint64_t po = PO[(size_t)x * PW + bw];
                Iv += (int)(po >> 48) + __popc((uint32_t)po & mask);
            }
        }
        cov = sgn * Iv;
    }
    cov += __shfl_xor(cov, 1);
    cov += __shfl_xor(cov, 2);
    if (i < npred && k == 0) {
        int area = (x2 - x1) * (y2 - y1);
        bool valid = (x2 > x1) && (y2 > y1);
        float iou = valid ? ((float)cov / fmaxf((float)area, 1.0f)) : 0.0f;
        l = (double)(1.0f - iou);
    }
    #pragma unroll
    for (int d = 32; d > 0; d >>= 1) l += __shfl_down(l, d);
    int lane = threadIdx.x & 63, wid = threadIdx.x >> 6;
    if (lane == 0) red[wid] = l;
    __syncthreads();
    if (threadIdx.x == 0) {
        atomicAdd(acc, red[0] + red[1] + red[2] + red[3]);
        __threadfence();
        if (atomicAdd(done, 1) == nblocks - 1) {
            double total = atomicAdd(acc, 0.0);   // coherent read of final sum
            out[0] = (float)(total / (double)npred);
        }
    }
}

extern "C" void kernel_launch(void* const* d_in, const int* in_sizes, int n_in,
                              void* d_out, int out_size, void* d_ws, size_t ws_size,
                              hipStream_t stream) {
    const float* pred = (const float*)d_in[0];
    // d_in[1] = target, unused by the reference loss
    const float* gt = (const float*)d_in[2];
    int npred = in_sizes[0] / 4;
    int ngt = in_sizes[2] / 4;

    char* ws = (char*)d_ws;
    size_t off = 0;
    auto alloc = [&](size_t bytes) {
        void* p = ws + off;
        off = (off + bytes + 255) & ~(size_t)255;
        return p;
    };
    int* Dcol = (int*)alloc((size_t)CH * CPAD * sizeof(int));            // 8.2 MB -> Hpre
    int* Ic = (int*)alloc((size_t)(CH + 1) * CPAD * sizeof(int));        // 8.2 MB
    uint64_t* PO = (uint64_t*)alloc((size_t)GN * PW * sizeof(uint64_t)); // 4.1 MB
    uint32_t* Crow = (uint32_t*)alloc((size_t)CH * (CPAD / 2) * sizeof(uint32_t)); // 4.1 MB
    uint16_t* bpts = (uint16_t*)alloc((size_t)CH * BKT * sizeof(uint16_t));
    int* bktcnt = (int*)alloc(512 * sizeof(int));
    double* acc = (double*)alloc(sizeof(double));
    int* done = (int*)alloc(sizeof(int));

    int nb = (4 * npred + 255) / 256;
    k_build<<<dim3(CH), dim3(256), 0, stream>>>(gt, ngt, Dcol, bktcnt, bpts, acc, done);
    k_vscanD<<<dim3(CPAD / 32), dim3(512), 0, stream>>>(Dcol);
    k_occ<<<dim3(CH), dim3(512), 0, stream>>>(gt, ngt, bpts, bktcnt, Dcol, PO, Crow);
    k_vscanC<<<dim3(CPAD / 32), dim3(512), 0, stream>>>(Crow, Ic);
    k_gather<<<dim3(nb), dim3(256), 0, stream>>>(pred, npred, Ic, PO, acc, done,
                                                 (float*)d_out, nb);
}

// Round 9
// 45.069 us; speedup vs baseline: 9.7558x; 1.3157x over previous
//
#include <hip/hip_runtime.h>
#include <stdint.h>

#define GN 4008      // reference GRID
#define RPC 8        // rows per chunk
#define CH 501       // x chunks; CH*RPC == GN
#define CPAD 4096    // padded column dim
#define PW 128       // PO u64 words per row
#define TW 512       // y-tile width; 8 tiles per row
#define HPAD 4352    // CPAD + CPAD/16
#define BCAP 256     // per-chunk bucket capacity (mean ~16)

static_assert(CH * RPC == GN, "chunking must cover grid");

__device__ __forceinline__ int padi(int y) { return y + (y >> 4); }

// Corner q of a box, JAX scatter semantics: negative index wraps (+GN),
// still-OOB (>=GN) dropped. q: 0=(x1,y1,+) 1=(x1,y2+1,-) 2=(x2+1,y1,-) 3=(x2+1,y2+1,+)
__device__ __forceinline__ bool corner1(const float4 b, int q,
                                        int& x, int& y, int& sg) {
    int x1 = (int)rintf(b.x * 100.0f);
    int y1 = (int)rintf(b.y * 100.0f);
    int x2 = (int)rintf(b.z * 100.0f);
    int y2 = (int)rintf(b.w * 100.0f);
    x = (q & 2) ? (x2 + 1) : x1;
    y = (q & 1) ? (y2 + 1) : y1;
    sg = (q == 0 || q == 3) ? 1 : -1;
    if (x < 0) x += GN;
    if (y < 0) y += GN;
    return (x >= 0 && x < GN && y >= 0 && y < GN);
}

// ---------------- K1: self-contained occ build: gt -> PO + Crow ------------
// Block c: (a) scan all corners; x<r0 -> LDS column histogram, in-chunk ->
// LDS bucket; (b) block h-scan of histogram -> seed row state; (c) 8 waves
// walk 8 rows x 512-col tiles -> occ bits (LDS); (d) emit PO (occ word |
// popc-prefix<<48) and Crow (h-scanned per-chunk column counts, u16 pairs).
__global__ __launch_bounds__(512, 2) void k_occ(const float* __restrict__ gt, int ngt,
                                                uint64_t* __restrict__ PO,
                                                uint32_t* __restrict__ Crow32,
                                                double* __restrict__ acc,
                                                int* __restrict__ done) {
    __shared__ int H[HPAD];          // column histogram -> h-scanned seed row
    __shared__ int R8[8 * 560];      // per-wave running col sums + row carries
    __shared__ uint32_t owq[1024];   // occ words: 8 rows x 128
    __shared__ uint32_t bkt[BCAP];
    __shared__ int nbkt;
    __shared__ int wsum8[8];
    __shared__ int wtot[8];
    const int c = blockIdx.x, t = threadIdx.x;
    const int tt = t >> 6, j = t & 63;
    const int r0 = c * RPC, y0 = tt * TW;
    int* R = R8 + tt * 560;          // 544 padded cols + 8 row carries
    int* cD = R + 544;
    for (int i = t; i < HPAD; i += 512) H[i] = 0;
    for (int i = j; i < 560; i += 64) R[i] = 0;
    if (t == 0) nbkt = 0;
    if (c == 0 && t == 0) { *acc = 0.0; *done = 0; }
    __syncthreads();
    // (a) corner scan: gt is 32KB, L2-broadcast across blocks
    for (int i = t; i < ngt; i += 512) {
        float4 b = ((const float4*)gt)[i];
        #pragma unroll
        for (int q = 0; q < 4; ++q) {
            int x, y, sg;
            if (corner1(b, q, x, y, sg)) {
                if (x < r0) {
                    atomicAdd(&H[padi(y)], sg);
                } else if (x < r0 + RPC) {
                    int pos = atomicAdd(&nbkt, 1);
                    if (pos < BCAP)
                        bkt[pos] = (uint32_t)(((x & 7) << 13) | (y << 1) | (sg > 0 ? 1 : 0));
                }
            }
        }
    }
    __syncthreads();
    // (b) block-wide inclusive h-scan of H (8 cols per thread)
    const int cb8 = t * 8;
    int hv[8];
    {
        int hs = 0;
        #pragma unroll
        for (int k = 0; k < 8; ++k) { hs += H[padi(cb8 + k)]; hv[k] = hs; }
        int ss = hs;
        #pragma unroll
        for (int d = 1; d < 64; d <<= 1) {
            int tmp = __shfl_up(ss, d);
            if (j >= d) ss += tmp;
        }
        if (j == 63) wsum8[tt] = ss;
        __syncthreads();          // raw-H reads done; wsum8 visible
        int hc = ss - hs;
        #pragma unroll
        for (int w = 0; w < 8; ++w) if (w < tt) hc += wsum8[w];
        #pragma unroll
        for (int k = 0; k < 8; ++k) H[padi(cb8 + k)] = hv[k] + hc;
    }
    __syncthreads();
    // (c) bucket distribute for this wave's tile
    int cnt = nbkt;
    bool fb = (cnt > BCAP);
    int pxr[4] = {-1, -1, -1, -1}, pry[4] = {0, 0, 0, 0}, psg[4] = {0, 0, 0, 0};
    if (!fb) {
        #pragma unroll
        for (int s = 0; s < 4; ++s) {
            int idx = j + 64 * s;
            if (idx < cnt) {
                uint32_t e = bkt[idx];
                int y = (int)((e >> 1) & 0xFFFu), xr = (int)(e >> 13);
                int sg = (e & 1u) ? 1 : -1;
                int ry = y - y0;
                if (ry >= 0 && ry < TW) { pxr[s] = xr; pry[s] = ry; psg[s] = sg; }
                else if (ry < 0) atomicAdd(&cD[xr], sg);
            }
        }
    } else {            // overflow fallback (correctness only)
        for (int i = j; i < 4 * ngt; i += 64) {
            float4 b = ((const float4*)gt)[i >> 2];
            int x, y, sg;
            if (corner1(b, i & 3, x, y, sg) && (x >> 3) == c) {
                int ry = y - y0;
                if (ry < 0) atomicAdd(&cD[x & 7], sg);
            }
        }
    }
    const int base = j * 8;
    int h[8];
    #pragma unroll
    for (int k = 0; k < 8; ++k) h[k] = H[padi(y0 + base + k)];
    __syncthreads();
    // (d) 8-row walk
    uint32_t cnt8[8] = {0, 0, 0, 0, 0, 0, 0, 0};
    int cb = 0;
    for (int xr = 0; xr < RPC; ++xr) {
        #pragma unroll
        for (int s = 0; s < 4; ++s)
            if (pxr[s] == xr) atomicAdd(&R[padi(pry[s])], psg[s]);
        if (fb) {
            for (int i = j; i < 4 * ngt; i += 64) {
                float4 b = ((const float4*)gt)[i >> 2];
                int x, y, sg;
                if (corner1(b, i & 3, x, y, sg) && x == r0 + xr) {
                    int ry = y - y0;
                    if (ry >= 0 && ry < TW) atomicAdd(&R[padi(ry)], sg);
                }
            }
        }
        __syncthreads();
        cb += cD[xr];
        int v[8], sl = 0;
        #pragma unroll
        for (int k = 0; k < 8; ++k) { sl += R[padi(base + k)]; v[k] = sl; }
        int ss = sl;
        #pragma unroll
        for (int d = 1; d < 64; d <<= 1) {
            int tmp = __shfl_up(ss, d);
            if (j >= d) ss += tmp;
        }
        int excl = ss - sl + cb;
        uint32_t m = 0;
        #pragma unroll
        for (int k = 0; k < 8; ++k) {
            int gy = y0 + base + k;
            if (gy < GN && (h[k] + excl + v[k]) > 0) m |= (1u << k);
        }
        #pragma unroll
        for (int k = 0; k < 8; ++k) cnt8[k] += (m >> k) & 1u;
        uint32_t wq = m << (8 * (j & 3));
        wq |= __shfl_xor(wq, 1);
        wq |= __shfl_xor(wq, 2);
        if ((j & 3) == 0)
            owq[xr * 128 + tt * 16 + (j >> 2)] = wq;
        __syncthreads();
    }
    // PO: wave tt emits row r0+tt
    {
        uint32_t w0 = owq[tt * 128 + 2 * j];
        uint32_t w1 = owq[tt * 128 + 2 * j + 1];
        int p0 = __popc(w0), p1 = __popc(w1);
        int tot = p0 + p1;
        int ss = tot;
        #pragma unroll
        for (int d = 1; d < 64; d <<= 1) {
            int tmp = __shfl_up(ss, d);
            if (j >= d) ss += tmp;
        }
        int excl = ss - tot;
        ulonglong2 o;
        o.x = (uint64_t)w0 | ((uint64_t)(uint32_t)excl << 48);
        o.y = (uint64_t)w1 | ((uint64_t)(uint32_t)(excl + p0) << 48);
        ((ulonglong2*)(PO + (size_t)(r0 + tt) * PW))[j] = o;
    }
    // Crow: block-wide h-scan of per-column chunk counts (u16 packed)
    {
        int ctot = 0;
        #pragma unroll
        for (int k = 0; k < 8; ++k) ctot += (int)cnt8[k];
        int ss = ctot;
        #pragma unroll
        for (int d = 1; d < 64; d <<= 1) {
            int tmp = __shfl_up(ss, d);
            if (j >= d) ss += tmp;
        }
        if (j == 63) wtot[tt] = ss;
        __syncthreads();
        int run = ss - ctot;
        #pragma unroll
        for (int w = 0; w < 8; ++w) if (w < tt) run += wtot[w];
        uint32_t pk[4];
        #pragma unroll
        for (int p = 0; p < 4; ++p) {
            run += (int)cnt8[2 * p];
            uint32_t lo = (uint32_t)run & 0xFFFFu;
            run += (int)cnt8[2 * p + 1];
            pk[p] = lo | (((uint32_t)run & 0xFFFFu) << 16);
        }
        *(uint4*)(Crow32 + (((size_t)c * CPAD + y0 + base) >> 1)) =
            make_uint4(pk[0], pk[1], pk[2], pk[3]);
    }
}

// ---------------- K2: vertical exclusive scan of Crow -> Ic ----------------
// 128 blocks x 512 thr; block owns 16 packed words (32 cols), 32 segs of 16.
__global__ __launch_bounds__(512) void k_vscanC(const uint32_t* __restrict__ Crow32,
                                                int* __restrict__ Ic) {
    __shared__ uint32_t ssum[32][16][2];
    int w = threadIdx.x & 15, s = threadIdx.x >> 4;
    int word = blockIdx.x * 16 + w;
    int c0 = s * 16, c1 = min(CH, c0 + 16);
    uint32_t s0 = 0, s1 = 0;
    for (int c = c0; c < c1; ++c) {
        uint32_t v = Crow32[(size_t)c * (CPAD / 2) + word];
        s0 += v & 0xFFFFu;
        s1 += v >> 16;
    }
    ssum[s][w][0] = s0;
    ssum[s][w][1] = s1;
    __syncthreads();
    uint32_t r0 = 0, r1 = 0;
    for (int k = 0; k < s; ++k) { r0 += ssum[k][w][0]; r1 += ssum[k][w][1]; }
    for (int c = c0; c < c1; ++c) {
        *(int2*)(Ic + (size_t)c * CPAD + 2 * word) = make_int2((int)r0, (int)r1);
        uint32_t v = Crow32[(size_t)c * (CPAD / 2) + word];
        r0 += v & 0xFFFFu;
        r1 += v >> 16;
    }
    if (c1 == CH)
        *(int2*)(Ic + (size_t)CH * CPAD + 2 * word) = make_int2((int)r0, (int)r1);
}

// ---------------- K3: gather (thread per box-corner) + reduce + finalize ---
__device__ __forceinline__ int clampI(int a) {
    return a < 0 ? 0 : (a > GN ? GN : a);
}

__global__ __launch_bounds__(256) void k_gather(const float* __restrict__ pred, int npred,
                                                const int* __restrict__ Ic,
                                                const uint64_t* __restrict__ PO,
                                                double* __restrict__ acc,
                                                int* __restrict__ done,
                                                float* __restrict__ out, int nblocks) {
    __shared__ double red[4];
    int g = blockIdx.x * 256 + threadIdx.x;
    int i = g >> 2, k = g & 3;
    double l = 0.0;
    int x1 = 0, y1 = 0, x2 = 0, y2 = 0;
    int cov = 0;
    if (i < npred) {
        float4 bx = ((const float4*)pred)[i];
        x1 = (int)rintf(bx.x * 100.0f);
        y1 = (int)rintf(bx.y * 100.0f);
        x2 = (int)rintf(bx.z * 100.0f);
        y2 = (int)rintf(bx.w * 100.0f);
        int a1 = clampI(x1), b1 = clampI(y1), a2 = clampI(x2), b2 = clampI(y2);
        int a = (k & 1) ? a1 : a2;
        int b = (k & 2) ? b1 : b2;
        int sgn = ((k ^ (k >> 1)) & 1) ? -1 : 1;
        int Iv = 0;
        if (a > 0 && b > 0) {
            int c = a >> 3;
            Iv = Ic[(size_t)c * CPAD + (b - 1)];
            int bw = b >> 5;
            uint32_t mask = (1u << (b & 31)) - 1u;   // b&31==0 -> 0
            for (int x = (a & ~7); x < a; ++x) {
                uint64_t po = PO[(size_t)x * PW + bw];
                Iv += (int)(po >> 48) + __popc((uint32_t)po & mask);
            }
        }
        cov = sgn * Iv;
    }
    cov += __shfl_xor(cov, 1);
    cov += __shfl_xor(cov, 2);
    if (i < npred && k == 0) {
        int area = (x2 - x1) * (y2 - y1);
        bool valid = (x2 > x1) && (y2 > y1);
        float iou = valid ? ((float)cov / fmaxf((float)area, 1.0f)) : 0.0f;
        l = (double)(1.0f - iou);
    }
    #pragma unroll
    for (int d = 32; d > 0; d >>= 1) l += __shfl_down(l, d);
    int lane = threadIdx.x & 63, wid = threadIdx.x >> 6;
    if (lane == 0) red[wid] = l;
    __syncthreads();
    if (threadIdx.x == 0) {
        atomicAdd(acc, red[0] + red[1] + red[2] + red[3]);
        __threadfence();
        if (atomicAdd(done, 1) == nblocks - 1) {
            double total = atomicAdd(acc, 0.0);   // coherent read of final sum
            out[0] = (float)(total / (double)npred);
        }
    }
}

extern "C" void kernel_launch(void* const* d_in, const int* in_sizes, int n_in,
                              void* d_out, int out_size, void* d_ws, size_t ws_size,
                              hipStream_t stream) {
    const float* pred = (const float*)d_in[0];
    // d_in[1] = target, unused by the reference loss
    const float* gt = (const float*)d_in[2];
    int npred = in_sizes[0] / 4;
    int ngt = in_sizes[2] / 4;

    char* ws = (char*)d_ws;
    size_t off = 0;
    auto alloc = [&](size_t bytes) {
        void* p = ws + off;
        off = (off + bytes + 255) & ~(size_t)255;
        return p;
    };
    int* Ic = (int*)alloc((size_t)(CH + 1) * CPAD * sizeof(int));        // 8.2 MB
    uint64_t* PO = (uint64_t*)alloc((size_t)GN * PW * sizeof(uint64_t)); // 4.1 MB
    uint32_t* Crow = (uint32_t*)alloc((size_t)CH * (CPAD / 2) * sizeof(uint32_t)); // 4.1 MB
    double* acc = (double*)alloc(sizeof(double));
    int* done = (int*)alloc(sizeof(int));

    int nb = (4 * npred + 255) / 256;
    k_occ<<<dim3(CH), dim3(512), 0, stream>>>(gt, ngt, PO, Crow, acc, done);
    k_vscanC<<<dim3(CPAD / 32), dim3(512), 0, stream>>>(Crow, Ic);
    k_gather<<<dim3(nb), dim3(256), 0, stream>>>(pred, npred, Ic, PO, acc, done,
                                                 (float*)d_out, nb);
}